// Round 11
// baseline (218.741 us; speedup 1.0000x reference)
//
#include <hip/hip_runtime.h>
#include <stdint.h>

typedef unsigned short ushort_t;
typedef __attribute__((ext_vector_type(4))) unsigned short ushort4_t;
typedef __attribute__((ext_vector_type(8))) short short8;
typedef __attribute__((ext_vector_type(4))) float float4_t;

#define AS1 __attribute__((address_space(1)))
#define AS3 __attribute__((address_space(3)))

__device__ inline ushort_t f2bf(float f) {
    unsigned x = __builtin_bit_cast(unsigned, f);
    unsigned r = x + 0x7fffu + ((x >> 16) & 1u);
    return (ushort_t)(r >> 16);
}
__device__ inline ushort_t f2bf_trunc(float f) {
    return (ushort_t)(__builtin_bit_cast(unsigned, f) >> 16);
}

// ---------- transpose+convert: in fp32 [R][C] -> out bf16 [C][R] ----------
__global__ __launch_bounds__(256) void transpose_f32_bf16(const float* __restrict__ in,
                                                          ushort_t* __restrict__ out,
                                                          int R, int C) {
    __shared__ __align__(16) ushort_t tile[64][65];
    int c0 = blockIdx.x * 64, r0 = blockIdx.y * 64;
    int t = threadIdx.x;
    for (int i = 0; i < 16; i++) {
        int idx = t + i * 256;
        int lr = idx >> 6, lc = idx & 63;
        tile[lr][lc] = f2bf(in[(size_t)(r0 + lr) * C + c0 + lc]);
    }
    __syncthreads();
    for (int i = 0; i < 16; i++) {
        int idx = t + i * 256;
        int lr = idx >> 6, lc = idx & 63;
        out[(size_t)(c0 + lr) * R + r0 + lc] = tile[lc][lr];
    }
}

// ---------- GEMM1: q/k/v = x(fp32, convert-staged) @ wqkvT^T, scatter to [b,h,n,d] ----------
__global__ __launch_bounds__(256) void gemm_qkv(
    const float* __restrict__ Afp, const ushort_t* __restrict__ Bt,
    ushort_t* __restrict__ outQ, ushort_t* __restrict__ outK, ushort_t* __restrict__ outV) {
    const int K = 1024;
    __shared__ __align__(16) ushort_t As[128 * 64];
    __shared__ __align__(16) ushort_t Bs[128 * 64];
    int t = threadIdx.x;
    int w = t >> 6, lane = t & 63;
    int quad = lane >> 4, l15 = lane & 15;
    int wM = w >> 1, wN = w & 1;
    int tM = blockIdx.y * 128, tN = blockIdx.x * 128;

    float4_t acc[4][4];
    for (int i = 0; i < 4; i++)
        for (int j = 0; j < 4; j++) acc[i][j] = (float4_t){0.f, 0.f, 0.f, 0.f};

    int lrow = lane >> 3;
    int lcol8 = (lane & 7) * 8;

    const ushort_t* Bbase = Bt + (size_t)(tN + w * 32) * K;

    for (int k0 = 0; k0 < K; k0 += 64) {
        __syncthreads();
        // A-stage: x fp32 -> bf16 (measured r5/r6: == glds path for this GEMM)
        for (int i = 0; i < 8; i++) {
            int e = t + i * 256;
            int row = e >> 4, c4 = (e & 15) * 4;
            const float4_t f = *(const float4_t*)&Afp[(size_t)(tM + row) * K + k0 + c4];
            ushort4_t u;
            u.x = f2bf(f.x); u.y = f2bf(f.y); u.z = f2bf(f.z); u.w = f2bf(f.w);
            *(ushort4_t*)&As[row * 64 + c4] = u;
        }
        for (int i = 0; i < 4; i++) {
            const ushort_t* gb = Bbase + (size_t)(i * 8 + lrow) * K + k0 + lcol8;
            __builtin_amdgcn_global_load_lds((AS1 void*)gb, (AS3 void*)&Bs[(w * 32 + i * 8) * 64], 16, 0, 0);
        }
        __syncthreads();
        for (int kt = 0; kt < 2; kt++) {
            short8 af[4], bf[4];
            for (int m = 0; m < 4; m++)
                af[m] = *(const short8*)&As[(wM * 64 + m * 16 + l15) * 64 + kt * 32 + quad * 8];
            for (int n = 0; n < 4; n++)
                bf[n] = *(const short8*)&Bs[(wN * 64 + n * 16 + l15) * 64 + kt * 32 + quad * 8];
            for (int m = 0; m < 4; m++)
                for (int n = 0; n < 4; n++)
                    acc[m][n] = __builtin_amdgcn_mfma_f32_16x16x32_bf16(af[m], bf[n], acc[m][n], 0, 0, 0);
        }
    }

    for (int m = 0; m < 4; m++) {
        int gm = tM + wM * 64 + m * 16 + quad * 4;
        for (int n = 0; n < 4; n++) {
            int gn = tN + wN * 64 + n * 16 + l15;
            int three = gn >> 10;
            int h = (gn >> 6) & 15;
            int dd = gn & 63;
            ushort_t* dst = (three == 0) ? outQ : (three == 1) ? outK : outV;
            for (int r = 0; r < 4; r++) {
                int row = gm + r;
                int b = row >> 11;
                int ns = row & 2047;
                dst[(((size_t)(b * 16 + h) * 2048 + ns) << 6) + dd] = f2bf(acc[m][n][r]);
            }
        }
    }
}

// ---------- flash attention (r6/r10 structure): paired q-tiles, deferred softmax, K/V dbuf ----------
// Grid swapped to (bh=32 fastest, pair=16): linear id ≡ bh (mod 8) -> all 16 pair-blocks
// of one bh land on one XCD -> K/V (512 KB/bh) stays L2-resident (4 bh x 512 KB <= 4 MB).
__global__ __launch_bounds__(256) void attn_kernel(
    const ushort_t* __restrict__ q, const ushort_t* __restrict__ k,
    const ushort_t* __restrict__ v, const int* __restrict__ pad,
    const int* __restrict__ csp, ushort_t* __restrict__ out) {
    __shared__ __align__(16) ushort_t Ks[2][64 * 64];    // [key][dd], XOR-swizzled
    __shared__ __align__(16) ushort_t VsT[2][64 * 64];   // [dd][key], XOR-swizzled
    __shared__ __align__(16) ushort_t Ps[4][2][16 * 64]; // per-wave, per-tile
    __shared__ float padb[2048];

    int cs = csp[0];
    int t = threadIdx.x, w = t >> 6, lane = t & 63;
    int quad = lane >> 4, l15 = lane & 15;
    int bh = blockIdx.x;                // bh fastest -> XCD locality
    int b = bh >> 4, h = bh & 15;
    int xp = blockIdx.y;
    int qtA = 31 - xp, qtB = xp;
    int q0A = qtA * 64, q0B = qtB * 64;
    const float c1 = 0.18033688f;    // 0.125 * log2(e)
    const float c2 = -11.541560f;    // -8 * log2(e)

    for (int i = 0; i < 8; i++) {
        int key = t + i * 256;
        padb[key] = pad[b * 2048 + key] ? -1e38f : c2;
    }

    const ushort_t* qbA = q + ((size_t)bh * 2048 + q0A + w * 16 + l15) * 64;
    short8 qA0 = *(const short8*)(qbA + quad * 8);
    short8 qA1 = *(const short8*)(qbA + 32 + quad * 8);
    const ushort_t* qbB = q + ((size_t)bh * 2048 + q0B + w * 16 + l15) * 64;
    short8 qB0 = *(const short8*)(qbB + quad * 8);
    short8 qB1 = *(const short8*)(qbB + 32 + quad * 8);

    float4_t OA[4], OB[4];
    for (int i = 0; i < 4; i++) { OA[i] = (float4_t){0.f,0.f,0.f,0.f}; OB[i] = (float4_t){0.f,0.f,0.f,0.f}; }
    float lsA[4] = {0.f,0.f,0.f,0.f}, lsB[4] = {0.f,0.f,0.f,0.f};

    int csT = (cs + 63) >> 6;
    int nTA = qtA + 1; if (csT > nTA) nTA = csT;
    int nTB = qtB + 1; if (csT > nTB) nTB = csT;
    int nTmax = nTA > nTB ? nTA : nTB;

    const ushort_t* kbase = k + (size_t)bh * 2048 * 64;
    const ushort_t* vbase = v + (size_t)bh * 2048 * 64;

    int lrow = lane >> 3, lblk = lane & 7;
    int prowA = q0A + w * 16 + quad * 4;
    int prowB = q0B + w * 16 + quad * 4;
    int sw = l15 & 7;

    short8 vr0, vr1;   // V register-prefetch
    auto stageK = [&](int it, int buf) {
        int k0 = it * 64;
        for (int i = 0; i < 2; i++) {
            int brow = w * 16 + i * 8;
            const ushort_t* gk = kbase + (size_t)(k0 + brow + lrow) * 64 + ((lblk ^ lrow) * 8);
            __builtin_amdgcn_global_load_lds((AS1 void*)gk, (AS3 void*)&Ks[buf][brow * 64], 16, 0, 0);
        }
    };
    auto loadV = [&](int it) {
        const ushort_t* vb = vbase + (size_t)(it * 64 + lane) * 64;
        vr0 = *(const short8*)(vb + w * 8);
        vr1 = *(const short8*)(vb + (w + 4) * 8);
    };

    stageK(0, 0);
    loadV(0);

    for (int it = 0; it < nTmax; it++) {
        int cur = it & 1, nxt = cur ^ 1;
        for (int j = 0; j < 8; j++) {
            int sl = (((lane >> 3) ^ j) * 8) + (lane & 7);
            VsT[cur][(w * 8 + j) * 64 + sl] = (ushort_t)vr0[j];
            VsT[cur][((w + 4) * 8 + j) * 64 + sl] = (ushort_t)vr1[j];
        }
        __syncthreads();  // drains this tile's K glds; VsT[cur] visible
        if (it + 1 < nTmax) {
            stageK(it + 1, nxt);
            loadV(it + 1);
        }

        int k0 = it * 64;
        bool actA = it < nTA, actB = it < nTB;

        short8 kf0[4], kf1[4];
        for (int ks = 0; ks < 4; ks++) {
            const ushort_t* krow = &Ks[cur][(ks * 16 + l15) * 64];
            kf0[ks] = *(const short8*)(krow + (quad ^ sw) * 8);
            kf1[ks] = *(const short8*)(krow + ((4 + quad) ^ sw) * 8);
        }

        if (actA) {
            float4_t s[4];
            for (int ks = 0; ks < 4; ks++) {
                float4_t a = (float4_t){0.f,0.f,0.f,0.f};
                a = __builtin_amdgcn_mfma_f32_16x16x32_bf16(qA0, kf0[ks], a, 0, 0, 0);
                a = __builtin_amdgcn_mfma_f32_16x16x32_bf16(qA1, kf1[ks], a, 0, 0, 0);
                s[ks] = a;
            }
            bool needC = (it >= qtA) && (k0 + 63 >= cs);
            for (int ks = 0; ks < 4; ks++) {
                int key = k0 + ks * 16 + l15;
                float add = padb[key];
                for (int r = 0; r < 4; r++) {
                    float arg = s[ks][r] * c1 + add;
                    if (needC && (key > prowA + r) && (key >= cs)) arg = -1e38f;
                    float p = __builtin_amdgcn_exp2f(arg);
                    lsA[r] += p;
                    int row = quad * 4 + r;
                    Ps[w][0][row * 64 + (((ks * 2 + (l15 >> 3)) ^ (row & 7)) * 8) + (l15 & 7)] = f2bf_trunc(p);
                }
            }
        }
        if (actB) {
            float4_t s[4];
            for (int ks = 0; ks < 4; ks++) {
                float4_t a = (float4_t){0.f,0.f,0.f,0.f};
                a = __builtin_amdgcn_mfma_f32_16x16x32_bf16(qB0, kf0[ks], a, 0, 0, 0);
                a = __builtin_amdgcn_mfma_f32_16x16x32_bf16(qB1, kf1[ks], a, 0, 0, 0);
                s[ks] = a;
            }
            bool needC = (it >= qtB) && (k0 + 63 >= cs);
            for (int ks = 0; ks < 4; ks++) {
                int key = k0 + ks * 16 + l15;
                float add = padb[key];
                for (int r = 0; r < 4; r++) {
                    float arg = s[ks][r] * c1 + add;
                    if (needC && (key > prowB + r) && (key >= cs)) arg = -1e38f;
                    float p = __builtin_amdgcn_exp2f(arg);
                    lsB[r] += p;
                    int row = quad * 4 + r;
                    Ps[w][1][row * 64 + (((ks * 2 + (l15 >> 3)) ^ (row & 7)) * 8) + (l15 & 7)] = f2bf_trunc(p);
                }
            }
        }

        short8 vf0[4], vf1[4];
        for (int n = 0; n < 4; n++) {
            const ushort_t* vrow = &VsT[cur][(n * 16 + l15) * 64];
            vf0[n] = *(const short8*)(vrow + (quad ^ sw) * 8);
            vf1[n] = *(const short8*)(vrow + ((4 + quad) ^ sw) * 8);
        }
        if (actA) {
            const ushort_t* prl = &Ps[w][0][l15 * 64];
            short8 pf0 = *(const short8*)(prl + (quad ^ sw) * 8);
            short8 pf1 = *(const short8*)(prl + ((4 + quad) ^ sw) * 8);
            for (int n = 0; n < 4; n++) {
                OA[n] = __builtin_amdgcn_mfma_f32_16x16x32_bf16(pf0, vf0[n], OA[n], 0, 0, 0);
                OA[n] = __builtin_amdgcn_mfma_f32_16x16x32_bf16(pf1, vf1[n], OA[n], 0, 0, 0);
            }
        }
        if (actB) {
            const ushort_t* prl = &Ps[w][1][l15 * 64];
            short8 pf0 = *(const short8*)(prl + (quad ^ sw) * 8);
            short8 pf1 = *(const short8*)(prl + ((4 + quad) ^ sw) * 8);
            for (int n = 0; n < 4; n++) {
                OB[n] = __builtin_amdgcn_mfma_f32_16x16x32_bf16(pf0, vf0[n], OB[n], 0, 0, 0);
                OB[n] = __builtin_amdgcn_mfma_f32_16x16x32_bf16(pf1, vf1[n], OB[n], 0, 0, 0);
            }
        }
    }

    for (int r = 0; r < 4; r++) {
        float l = lsA[r];
        l += __shfl_xor(l, 1, 64); l += __shfl_xor(l, 2, 64);
        l += __shfl_xor(l, 4, 64); l += __shfl_xor(l, 8, 64);
        float inv = l > 0.f ? 1.f / l : 0.f;
        int row = q0A + w * 16 + quad * 4 + r;
        size_t ob = ((size_t)b * 2048 + row) * 1024 + h * 64;
        for (int n = 0; n < 4; n++)
            out[ob + n * 16 + l15] = f2bf(OA[n][r] * inv);
    }
    for (int r = 0; r < 4; r++) {
        float l = lsB[r];
        l += __shfl_xor(l, 1, 64); l += __shfl_xor(l, 2, 64);
        l += __shfl_xor(l, 4, 64); l += __shfl_xor(l, 8, 64);
        float inv = l > 0.f ? 1.f / l : 0.f;
        int row = q0B + w * 16 + quad * 4 + r;
        size_t ob = ((size_t)b * 2048 + row) * 1024 + h * 64;
        for (int n = 0; n < 4; n++)
            out[ob + n * 16 + l15] = f2bf(OB[n][r] * inv);
    }
}

// ---------- GEMM2: out = ao @ wprojT^T + bias; 64x128 tiles, grid (8,64) = 2 blocks/CU ----------
__global__ __launch_bounds__(256) void gemm_out_k(
    const ushort_t* __restrict__ A, const ushort_t* __restrict__ Bt,
    const float* __restrict__ bias, float* __restrict__ outC) {
    const int K = 1024, N = 1024;
    __shared__ __align__(16) ushort_t As[64 * 64];
    __shared__ __align__(16) ushort_t Bs[128 * 64];
    int t = threadIdx.x;
    int w = t >> 6, lane = t & 63;
    int quad = lane >> 4, l15 = lane & 15;
    int wM = w >> 1, wN = w & 1;   // wave grid 2x2 over 64M x 128N
    int tM = blockIdx.y * 64, tN = blockIdx.x * 128;

    float4_t acc[2][4];
    for (int i = 0; i < 2; i++)
        for (int j = 0; j < 4; j++) acc[i][j] = (float4_t){0.f, 0.f, 0.f, 0.f};

    int lrow = lane >> 3;
    int lcol8 = (lane & 7) * 8;

    const ushort_t* Abase = A + (size_t)(tM + w * 16) * K;
    const ushort_t* Bbase = Bt + (size_t)(tN + w * 32) * K;

    for (int k0 = 0; k0 < K; k0 += 64) {
        __syncthreads();
        for (int i = 0; i < 2; i++) {
            const ushort_t* ga = Abase + (size_t)(i * 8 + lrow) * K + k0 + lcol8;
            __builtin_amdgcn_global_load_lds((AS1 void*)ga, (AS3 void*)&As[(w * 16 + i * 8) * 64], 16, 0, 0);
        }
        for (int i = 0; i < 4; i++) {
            const ushort_t* gb = Bbase + (size_t)(i * 8 + lrow) * K + k0 + lcol8;
            __builtin_amdgcn_global_load_lds((AS1 void*)gb, (AS3 void*)&Bs[(w * 32 + i * 8) * 64], 16, 0, 0);
        }
        __syncthreads();
        for (int kt = 0; kt < 2; kt++) {
            short8 af[2], bf[4];
            for (int m = 0; m < 2; m++)
                af[m] = *(const short8*)&As[(wM * 32 + m * 16 + l15) * 64 + kt * 32 + quad * 8];
            for (int n = 0; n < 4; n++)
                bf[n] = *(const short8*)&Bs[(wN * 64 + n * 16 + l15) * 64 + kt * 32 + quad * 8];
            for (int m = 0; m < 2; m++)
                for (int n = 0; n < 4; n++)
                    acc[m][n] = __builtin_amdgcn_mfma_f32_16x16x32_bf16(af[m], bf[n], acc[m][n], 0, 0, 0);
        }
    }

    for (int m = 0; m < 2; m++) {
        int gm = tM + wM * 32 + m * 16 + quad * 4;
        for (int n = 0; n < 4; n++) {
            int gn = tN + wN * 64 + n * 16 + l15;
            float bv = bias[gn];
            for (int r = 0; r < 4; r++)
                outC[(size_t)(gm + r) * N + gn] = acc[m][n][r] + bv;
        }
    }
}

extern "C" void kernel_launch(void* const* d_in, const int* in_sizes, int n_in,
                              void* d_out, int out_size, void* d_ws, size_t ws_size,
                              hipStream_t stream) {
    const float* x = (const float*)d_in[0];
    const int* pad = (const int*)d_in[1];
    const int* cs = (const int*)d_in[2];
    const float* wqkv = (const float*)d_in[3];
    const float* wproj = (const float*)d_in[4];
    const float* bproj = (const float*)d_in[5];
    float* out = (float*)d_out;

    // ws (peak 32 MB, lifetimes audited):
    //   q[0,8M) k[8,16M) v[16,24M)        gemm1 -> attn
    //   wqkvT[24,30M)                     transpose -> gemm1 (dies)
    //   ao bf16 [24,32M)                  attn -> gemm2 (over dead wqkvT)
    //   wprojT[0,2M)                      transposed AFTER attn (over dead q)
    // d_out: final fp32 out only (xbf eliminated — gemm1 converts x in-stage).
    ushort_t* ws = (ushort_t*)d_ws;
    ushort_t* qws = ws;
    ushort_t* kws = ws + (size_t)4194304;
    ushort_t* vws = ws + (size_t)8388608;
    ushort_t* wqkvT = ws + (size_t)12582912;
    ushort_t* aows = ws + (size_t)12582912;
    ushort_t* wprojT = ws;

    transpose_f32_bf16<<<dim3(48, 16), 256, 0, stream>>>(wqkv, wqkvT, 1024, 3072);
    gemm_qkv<<<dim3(24, 32), 256, 0, stream>>>(x, wqkvT, qws, kws, vws);
    attn_kernel<<<dim3(32, 16), 256, 0, stream>>>(qws, kws, vws, pad, cs, aows);
    transpose_f32_bf16<<<dim3(16, 16), 256, 0, stream>>>(wproj, wprojT, 1024, 1024);
    gemm_out_k<<<dim3(8, 64), 256, 0, stream>>>(aows, wprojT, bproj, out);
}